// Round 1
// baseline (3758.050 us; speedup 1.0000x reference)
//
#include <hip/hip_runtime.h>

// Problem constants (from reference):
//   coordinates (B=8, N=8192, D=3) f32, features (B=8, N=8192, C=128) f32
//   out: coords (B, M=2048, 3) ++ features (B, M, C=128), flat f32
#define BB 8
#define NN 8192
#define MM 2048
#define KK 32
#define CC 128

// ---------------------------------------------------------------------------
// FPS: one workgroup per batch, 256 threads, 32 points/thread held in VGPRs.
// Replicates jnp semantics bit-exactly where possible:
//   dist = min(dist, sqrt((x-cx)^2+(y-cy)^2+(z-cz)^2))  [no FMA, IEEE sqrt]
//   argmax with first-index tie-break (packed u64: valbits<<32 | ~idx)
// ---------------------------------------------------------------------------
__global__ __launch_bounds__(256, 1)
void fps_kernel(const float* __restrict__ coords, int* __restrict__ fps_idx) {
  const int b = blockIdx.x;
  const int t = threadIdx.x;
  const float* cb = coords + (size_t)b * NN * 3;

  float x[32], y[32], z[32], dist[32];
#pragma unroll
  for (int j = 0; j < 32; ++j) {
    const int p = t + j * 256;
    x[j] = cb[p * 3 + 0];
    y[j] = cb[p * 3 + 1];
    z[j] = cb[p * 3 + 2];
    dist[j] = 1e10f;
  }

  __shared__ unsigned long long s_part[4];

  if (t == 0) fps_idx[b * MM + 0] = 0;  // farthest_0 = 0
  float cx = cb[0], cy = cb[1], cz = cb[2];

  for (int it = 1; it < MM; ++it) {
    // --- update dists with current centroid; track local argmax ---
    float bestv = -1.0f;
    unsigned int besti = 0u;
#pragma unroll
    for (int j = 0; j < 32; ++j) {
      const float dx = __fsub_rn(x[j], cx);
      const float dy = __fsub_rn(y[j], cy);
      const float dz = __fsub_rn(z[j], cz);
      // exact ref order: (dx*dx + dy*dy) + dz*dz, no FMA contraction
      const float d2 = __fadd_rn(__fadd_rn(__fmul_rn(dx, dx), __fmul_rn(dy, dy)),
                                 __fmul_rn(dz, dz));
      const float cd = __fsqrt_rn(d2);          // IEEE, matches jnp.linalg.norm
      const float nd = fminf(dist[j], cd);
      dist[j] = nd;
      // strict > keeps earliest (smallest) index within this thread's ascending scan
      if (nd > bestv) { bestv = nd; besti = (unsigned)(t + j * 256); }
    }

    // pack: larger value wins; equal value -> larger ~idx = smaller idx wins
    unsigned long long best =
        ((unsigned long long)__float_as_uint(bestv) << 32) | (unsigned)(~besti);

    // --- wave max-reduce (64 lanes) ---
#pragma unroll
    for (int off = 1; off < 64; off <<= 1) {
      const unsigned long long o = __shfl_xor(best, off);
      if (o > best) best = o;
    }
    if ((t & 63) == 0) s_part[t >> 6] = best;
    __syncthreads();
    const unsigned long long b01 = s_part[0] > s_part[1] ? s_part[0] : s_part[1];
    const unsigned long long b23 = s_part[2] > s_part[3] ? s_part[2] : s_part[3];
    const unsigned long long g = b01 > b23 ? b01 : b23;
    __syncthreads();  // protect s_part reuse next iteration

    const int widx = (int)(~(unsigned int)(g & 0xFFFFFFFFull));
    if (t == 0) fps_idx[b * MM + it] = widx;

    // broadcast centroid coords (uniform address -> scalar path)
    const int ridx = __builtin_amdgcn_readfirstlane(widx);
    cx = cb[ridx * 3 + 0];
    cy = cb[ridx * 3 + 1];
    cz = cb[ridx * 3 + 2];
  }
}

// ---------------------------------------------------------------------------
// Gather sampled coordinates into d_out[0 .. B*M*3)
// ---------------------------------------------------------------------------
__global__ void gather_coords_kernel(const float* __restrict__ coords,
                                     const int* __restrict__ fps_idx,
                                     float* __restrict__ out_coords) {
  const int i = blockIdx.x * 256 + threadIdx.x;
  if (i >= BB * MM) return;
  const int b = i >> 11;  // / MM
  const int p = fps_idx[i];
  const float* src = coords + ((size_t)b * NN + p) * 3;
  out_coords[i * 3 + 0] = src[0];
  out_coords[i * 3 + 1] = src[1];
  out_coords[i * 3 + 2] = src[2];
}

// ---------------------------------------------------------------------------
// KNN top-32 (stable, index tie-break like lax.top_k) + feature mean.
// One 256-thread WG per query; 32 d2-keys per thread in VGPRs.
// d2 = c2 + p2 - 2*dot, dot mirrored as k-ascending FMA chain (GEMM-like).
// ---------------------------------------------------------------------------
__global__ __launch_bounds__(256, 4)
void knn_mean_kernel(const float* __restrict__ coords,
                     const float* __restrict__ feats,
                     const int* __restrict__ fps_idx,
                     float* __restrict__ out_feats) {
  const int q = blockIdx.x;   // b*MM + m
  const int b = q >> 11;
  const int t = threadIdx.x;
  const float* cb = coords + (size_t)b * NN * 3;

  const int ci = fps_idx[q];
  const float cx = cb[ci * 3 + 0], cy = cb[ci * 3 + 1], cz = cb[ci * 3 + 2];
  const float c2 = __fadd_rn(__fadd_rn(__fmul_rn(cx, cx), __fmul_rn(cy, cy)),
                             __fmul_rn(cz, cz));

  unsigned long long key[32];
#pragma unroll
  for (int j = 0; j < 32; ++j) {
    const int p = t + j * 256;
    const float px = cb[p * 3 + 0], py = cb[p * 3 + 1], pz = cb[p * 3 + 2];
    const float p2 = __fadd_rn(__fadd_rn(__fmul_rn(px, px), __fmul_rn(py, py)),
                               __fmul_rn(pz, pz));
    const float dot = __fmaf_rn(cz, pz, __fmaf_rn(cy, py, __fmul_rn(cx, px)));
    const float d2 = __fsub_rn(__fadd_rn(c2, p2), __fadd_rn(dot, dot));
    // order-preserving bit transform (handles tiny-negative self-distance)
    unsigned int ub = __float_as_uint(d2);
    ub ^= (((unsigned)((int)ub >> 31)) | 0x80000000u);
    key[j] = ((unsigned long long)ub << 32) | (unsigned int)p;
  }

  unsigned long long lmin = key[0];
#pragma unroll
  for (int j = 1; j < 32; ++j) lmin = key[j] < lmin ? key[j] : lmin;

  __shared__ unsigned long long s_part[4];
  __shared__ int s_nbr[KK];

  for (int r = 0; r < KK; ++r) {
    unsigned long long v = lmin;
#pragma unroll
    for (int off = 1; off < 64; off <<= 1) {
      const unsigned long long o = __shfl_xor(v, off);
      if (o < v) v = o;
    }
    if ((t & 63) == 0) s_part[t >> 6] = v;
    __syncthreads();
    const unsigned long long g01 = s_part[0] < s_part[1] ? s_part[0] : s_part[1];
    const unsigned long long g23 = s_part[2] < s_part[3] ? s_part[2] : s_part[3];
    const unsigned long long g = g01 < g23 ? g01 : g23;
    const int widx = (int)(g & 0xFFFFFFFFull);

    if (t == (widx & 255)) {           // owner removes winner, repairs local min
#pragma unroll
      for (int j = 0; j < 32; ++j)
        if (key[j] == g) key[j] = ~0ULL;
      lmin = key[0];
#pragma unroll
      for (int j = 1; j < 32; ++j) lmin = key[j] < lmin ? key[j] : lmin;
    }
    if (t == 0) s_nbr[r] = widx;
    __syncthreads();                   // protects s_part + publishes s_nbr[r]
  }

  // --- feature mean: thread t -> channel t&127, half t>>7 sums 16 rows ---
  const int c = t & (CC - 1);
  const int half = t >> 7;
  const float* fb = feats + (size_t)b * NN * CC;
  float s = 0.0f;
#pragma unroll
  for (int k = 0; k < 16; ++k) {
    const int p = s_nbr[half * 16 + k];
    s = __fadd_rn(s, fb[(size_t)p * CC + c]);
  }
  __shared__ float s_sum[CC];
  if (half == 1) s_sum[c] = s;
  __syncthreads();
  if (half == 0) {
    const float tot = __fadd_rn(s, s_sum[c]);           // (k0..15)+(k16..31)
    out_feats[(size_t)q * CC + c] = tot * 0.03125f;     // exact /32
  }
}

// ---------------------------------------------------------------------------
extern "C" void kernel_launch(void* const* d_in, const int* in_sizes, int n_in,
                              void* d_out, int out_size, void* d_ws, size_t ws_size,
                              hipStream_t stream) {
  const float* coords = (const float*)d_in[0];
  const float* feats  = (const float*)d_in[1];
  float* out_coords = (float*)d_out;                          // B*M*3
  float* out_feats  = (float*)d_out + (size_t)BB * MM * 3;    // B*M*C
  int* fps_idx = (int*)d_ws;                                  // B*M int32 (64 KB)

  fps_kernel<<<BB, 256, 0, stream>>>(coords, fps_idx);
  gather_coords_kernel<<<(BB * MM + 255) / 256, 256, 0, stream>>>(coords, fps_idx,
                                                                  out_coords);
  knn_mean_kernel<<<BB * MM, 256, 0, stream>>>(coords, feats, fps_idx, out_feats);
}

// Round 4
// 3510.351 us; speedup vs baseline: 1.0706x; 1.0706x over previous
//
#include <hip/hip_runtime.h>

// coordinates (B=8, N=8192, 3) f32, features (B=8, N=8192, C=128) f32
// out: coords (B, M=2048, 3) ++ features (B, M, C=128), flat f32
#define BB 8
#define NN 8192
#define MM 2048
#define KK 32
#define CC 128

#define FPS_T 512           // threads per FPS workgroup
#define FPS_P (NN / FPS_T)  // 16 points per thread

// ---------------------------------------------------------------------------
// FPS in squared-distance space with exact sqrt-space tie repair.
//   reference: dist = min(dist, sqrt_rn(d2)); winner = argmax(dist), first idx
//   ours:      d2m  = min(d2m, d2);  gmax = max(d2m)
//              s = sqrt_rn(gmax); lo_f = smallest float a with sqrt_rn(a)==s
//              winner = min index with d2m >= lo_f   (== reference winner)
// Owner thread broadcasts centroid from registers via LDS (no global load on
// the critical path) and writes fps_idx + out_coords directly.
// ---------------------------------------------------------------------------
__global__ __launch_bounds__(FPS_T, 1)
void fps_kernel(const float* __restrict__ coords, int* __restrict__ fps_idx,
                float* __restrict__ out_coords) {
  const int b = blockIdx.x;
  const int t = threadIdx.x;
  const float* cb = coords + (size_t)b * NN * 3;

  float x[FPS_P], y[FPS_P], z[FPS_P], d2m[FPS_P];
#pragma unroll
  for (int j = 0; j < FPS_P; ++j) {
    const int p = t + j * FPS_T;
    x[j] = cb[p * 3 + 0];
    y[j] = cb[p * 3 + 1];
    z[j] = cb[p * 3 + 2];
    d2m[j] = 1e20f;  // sqrt-space init 1e10 == d2-space 1e20 (always replaced)
  }

  __shared__ float s_part[FPS_T / 64];
  __shared__ float s_cent[3];
  __shared__ unsigned int s_widx;

  if (t == 0) {
    fps_idx[b * MM + 0] = 0;
    out_coords[(size_t)(b * MM) * 3 + 0] = cb[0];
    out_coords[(size_t)(b * MM) * 3 + 1] = cb[1];
    out_coords[(size_t)(b * MM) * 3 + 2] = cb[2];
    s_widx = 0xFFFFFFFFu;
  }
  float cx = cb[0], cy = cb[1], cz = cb[2];
  __syncthreads();  // s_widx init visible

  for (int it = 1; it < MM; ++it) {
    // --- update squared dists; track thread-local max ---
    float bestv = -1.0f;
#pragma unroll
    for (int j = 0; j < FPS_P; ++j) {
      const float dx = __fsub_rn(x[j], cx);
      const float dy = __fsub_rn(y[j], cy);
      const float dz = __fsub_rn(z[j], cz);
      const float d2 = __fadd_rn(__fadd_rn(__fmul_rn(dx, dx), __fmul_rn(dy, dy)),
                                 __fmul_rn(dz, dz));
      const float nd = fminf(d2m[j], d2);
      d2m[j] = nd;
      bestv = fmaxf(bestv, nd);
    }

    // --- wave max-reduce (f32 only; 1 bpermute per level) ---
    float v = bestv;
#pragma unroll
    for (int off = 1; off < 64; off <<= 1) v = fmaxf(v, __shfl_xor(v, off));
    if ((t & 63) == 0) s_part[t >> 6] = v;
    __syncthreads();  // A: partials ready; prev-iter s_widx reset visible

    float gmax = s_part[0];
#pragma unroll
    for (int w = 1; w < FPS_T / 64; ++w) gmax = fmaxf(gmax, s_part[w]);

    // --- exact sqrt-space tie threshold (uniform scalar math) ---
    float lo_f;
    if (!(gmax > 0.0f)) {
      lo_f = 0.0f;
    } else {
      const float s = __fsqrt_rn(gmax);                       // == ref max dist
      const float sp = __int_as_float(__float_as_int(s) - 1); // nextafter down
      const double mid = 0.5 * ((double)s + (double)sp);      // exact (<=25 bits)
      const double lod = mid * mid;                           // exact (<=50 bits)
      float c = (float)lod;
      if ((double)c < lod) c = __int_as_float(__float_as_int(c) + 1);  // ceil
      lo_f = c;                                               // d2>=lo_f <=> sqrt_rn(d2)==s
    }

    // --- locate: min index among d2m >= lo_f ---
    if (bestv >= lo_f) {
      unsigned int mi = 0xFFFFFFFFu;
#pragma unroll
      for (int j = 0; j < FPS_P; ++j) {
        const unsigned int pi = (unsigned int)(t + j * FPS_T);
        if (d2m[j] >= lo_f && pi < mi) mi = pi;
      }
      atomicMin(&s_widx, mi);
    }
    __syncthreads();  // B: winner final

    const unsigned int widx = s_widx;
    const int ot = (int)(widx & (FPS_T - 1));
    const int oj = (int)(widx >> 9);  // log2(FPS_T) = 9
    if (t == ot) {
      s_cent[0] = x[oj];
      s_cent[1] = y[oj];
      s_cent[2] = z[oj];
      fps_idx[b * MM + it] = (int)widx;
      float* oc = out_coords + (size_t)(b * MM + it) * 3;
      oc[0] = x[oj]; oc[1] = y[oj]; oc[2] = z[oj];
    }
    __syncthreads();  // C: centroid published; all reads of s_widx done
    cx = s_cent[0]; cy = s_cent[1]; cz = s_cent[2];
    if (t == 0) s_widx = 0xFFFFFFFFu;  // next atomics are after barrier A
  }
}

// ---------------------------------------------------------------------------
// KNN top-32 (exact (d2, idx) lexicographic order == lax.top_k) + feature mean.
// Value-then-locate rounds on plain f32 keys (no u64 -> no VGPR spill).
// Double-buffered winner slot keeps it at 2 barriers/round.
// ---------------------------------------------------------------------------
__global__ __launch_bounds__(256, 4)
void knn_mean_kernel(const float* __restrict__ coords,
                     const float* __restrict__ feats,
                     const float* __restrict__ out_coords,
                     float* __restrict__ out_feats) {
  const int q = blockIdx.x;   // b*MM + m
  const int b = q >> 11;
  const int t = threadIdx.x;
  const float* cb = coords + (size_t)b * NN * 3;

  const float cx = out_coords[(size_t)q * 3 + 0];
  const float cy = out_coords[(size_t)q * 3 + 1];
  const float cz = out_coords[(size_t)q * 3 + 2];
  const float c2 = __fadd_rn(__fadd_rn(__fmul_rn(cx, cx), __fmul_rn(cy, cy)),
                             __fmul_rn(cz, cz));

  float d2a[32];
  float lmin = 1e30f;
#pragma unroll
  for (int j = 0; j < 32; ++j) {
    const int p = t + j * 256;
    const float px = cb[p * 3 + 0], py = cb[p * 3 + 1], pz = cb[p * 3 + 2];
    const float p2 = __fadd_rn(__fadd_rn(__fmul_rn(px, px), __fmul_rn(py, py)),
                               __fmul_rn(pz, pz));
    const float dot = __fmaf_rn(cz, pz, __fmaf_rn(cy, py, __fmul_rn(cx, px)));
    const float d2 = __fsub_rn(__fadd_rn(c2, p2), __fadd_rn(dot, dot));
    d2a[j] = d2;
    lmin = fminf(lmin, d2);
  }

  __shared__ float s_pmin[4];
  __shared__ unsigned int s_w[2];
  __shared__ int s_nbr[KK];
  if (t < 2) s_w[t] = 0xFFFFFFFFu;
  __syncthreads();

  for (int r = 0; r < KK; ++r) {
    float v = lmin;
#pragma unroll
    for (int off = 1; off < 64; off <<= 1) v = fminf(v, __shfl_xor(v, off));
    if ((t & 63) == 0) s_pmin[t >> 6] = v;
    __syncthreads();  // A: partials ready; round r-1 reads of its slot done

    if (t == 0 && r > 0) s_w[(r - 1) & 1] = 0xFFFFFFFFu;  // recycle old slot

    const float gmin = fminf(fminf(s_pmin[0], s_pmin[1]),
                             fminf(s_pmin[2], s_pmin[3]));
    if (lmin == gmin) {
      unsigned int mi = 0xFFFFFFFFu;
#pragma unroll
      for (int j = 0; j < 32; ++j) {
        const unsigned int pi = (unsigned int)(t + j * 256);
        if (d2a[j] == gmin && pi < mi) mi = pi;
      }
      atomicMin(&s_w[r & 1], mi);
    }
    __syncthreads();  // B: winner final

    const unsigned int widx = s_w[r & 1];
    if (t == (int)(widx & 255u)) {  // owner removes winner, repairs local min
      const int oj = (int)(widx >> 8);
      d2a[oj] = 1e30f;
      float nm = 1e30f;
#pragma unroll
      for (int j = 0; j < 32; ++j) nm = fminf(nm, d2a[j]);
      lmin = nm;
    }
    if (t == 0) s_nbr[r] = (int)widx;
  }
  __syncthreads();  // s_nbr complete

  // --- feature mean: thread t -> channel t&127, half t>>7 sums 16 rows ---
  const int c = t & (CC - 1);
  const int half = t >> 7;
  const float* fb = feats + (size_t)b * NN * CC;
  float s = 0.0f;
#pragma unroll
  for (int k = 0; k < 16; ++k) {
    const int p = s_nbr[half * 16 + k];
    s = __fadd_rn(s, fb[(size_t)p * CC + c]);
  }
  __shared__ float s_sum[CC];
  if (half == 1) s_sum[c] = s;
  __syncthreads();
  if (half == 0) {
    const float tot = __fadd_rn(s, s_sum[c]);        // (k0..15)+(k16..31)
    out_feats[(size_t)q * CC + c] = tot * 0.03125f;  // exact /32
  }
}

// ---------------------------------------------------------------------------
extern "C" void kernel_launch(void* const* d_in, const int* in_sizes, int n_in,
                              void* d_out, int out_size, void* d_ws, size_t ws_size,
                              hipStream_t stream) {
  const float* coords = (const float*)d_in[0];
  const float* feats  = (const float*)d_in[1];
  float* out_coords = (float*)d_out;                        // B*M*3
  float* out_feats  = (float*)d_out + (size_t)BB * MM * 3;  // B*M*C
  int* fps_idx = (int*)d_ws;                                // B*M int32

  fps_kernel<<<BB, FPS_T, 0, stream>>>(coords, fps_idx, out_coords);
  knn_mean_kernel<<<BB * MM, 256, 0, stream>>>(coords, feats, out_coords,
                                               out_feats);
}

// Round 5
// 2655.183 us; speedup vs baseline: 1.4154x; 1.3221x over previous
//
#include <hip/hip_runtime.h>

// coordinates (B=8, N=8192, 3) f32, features (B=8, N=8192, C=128) f32
// out: coords (B, M=2048, 3) ++ features (B, M, C=128), flat f32
#define BB 8
#define NN 8192
#define MM 2048
#define KK 32
#define CC 128

#define FPS_T 512           // threads per FPS workgroup (8 waves)
#define FPS_P (NN / FPS_T)  // 16 points per thread

// ---------------------------------------------------------------------------
// DPP helpers: full-wave (64-lane) reductions, result valid in lane 63.
// row_shr:1/2/4/8 then row_bcast15 (rows 1,3) + row_bcast31 (rows 2,3).
// Pure VALU (~50 cyc) vs 6x ds_bpermute (~240 cyc) for __shfl_xor loops.
// ---------------------------------------------------------------------------
template <int Ctrl, int RowMask>
__device__ __forceinline__ int dpp_i(int x) {
  return __builtin_amdgcn_update_dpp(x, x, Ctrl, RowMask, 0xf, false);
}

__device__ __forceinline__ float wave_max63(float v) {
  v = fmaxf(v, __int_as_float(dpp_i<0x111, 0xf>(__float_as_int(v))));  // shr1
  v = fmaxf(v, __int_as_float(dpp_i<0x112, 0xf>(__float_as_int(v))));  // shr2
  v = fmaxf(v, __int_as_float(dpp_i<0x114, 0xf>(__float_as_int(v))));  // shr4
  v = fmaxf(v, __int_as_float(dpp_i<0x118, 0xf>(__float_as_int(v))));  // shr8
  v = fmaxf(v, __int_as_float(dpp_i<0x142, 0xa>(__float_as_int(v))));  // bcast15
  v = fmaxf(v, __int_as_float(dpp_i<0x143, 0xc>(__float_as_int(v))));  // bcast31
  return v;  // lane 63 holds wave max
}

__device__ __forceinline__ unsigned int wave_minu63(unsigned int v) {
  unsigned int o;
  o = (unsigned int)dpp_i<0x111, 0xf>((int)v); v = o < v ? o : v;
  o = (unsigned int)dpp_i<0x112, 0xf>((int)v); v = o < v ? o : v;
  o = (unsigned int)dpp_i<0x114, 0xf>((int)v); v = o < v ? o : v;
  o = (unsigned int)dpp_i<0x118, 0xf>((int)v); v = o < v ? o : v;
  o = (unsigned int)dpp_i<0x142, 0xa>((int)v); v = o < v ? o : v;
  o = (unsigned int)dpp_i<0x143, 0xc>((int)v); v = o < v ? o : v;
  return v;  // lane 63 holds wave min
}

template <int Ctrl, int RowMask>
__device__ __forceinline__ unsigned long long dpp_u64(unsigned long long v) {
  const int lo = (int)(unsigned int)v;
  const int hi = (int)(unsigned int)(v >> 32);
  const unsigned int nlo = (unsigned int)dpp_i<Ctrl, RowMask>(lo);
  const unsigned int nhi = (unsigned int)dpp_i<Ctrl, RowMask>(hi);
  return ((unsigned long long)nhi << 32) | nlo;
}

__device__ __forceinline__ unsigned long long wave_minu64_63(unsigned long long v) {
  unsigned long long o;
  o = dpp_u64<0x111, 0xf>(v); v = o < v ? o : v;
  o = dpp_u64<0x112, 0xf>(v); v = o < v ? o : v;
  o = dpp_u64<0x114, 0xf>(v); v = o < v ? o : v;
  o = dpp_u64<0x118, 0xf>(v); v = o < v ? o : v;
  o = dpp_u64<0x142, 0xa>(v); v = o < v ? o : v;
  o = dpp_u64<0x143, 0xc>(v); v = o < v ? o : v;
  return v;  // lane 63 holds wave min
}

// ---------------------------------------------------------------------------
// FPS in squared-distance space with exact sqrt-space tie repair (verbatim
// arithmetic from the round-4 PASSING kernel). Per-iteration serial chain:
//   update(issue) -> DPP max -> LDS+barrier A -> gmax -> lo_f -> locate
//   -> DPP idx-min -> LDS+barrier B -> widx -> centroid from LDS coords.
// 2 barriers, 0 atomics, centroid broadcast via uniform-address LDS read.
// ---------------------------------------------------------------------------
__global__ __launch_bounds__(FPS_T, 1)
void fps_kernel(const float* __restrict__ coords, float* __restrict__ out_coords) {
  const int b = blockIdx.x;
  const int t = threadIdx.x;
  const float* cb = coords + (size_t)b * NN * 3;

  __shared__ float s_x[NN], s_y[NN], s_z[NN];     // 96 KB coords mirror
  __shared__ float s_gpart[FPS_T / 64];
  __shared__ unsigned int s_ipart[FPS_T / 64];

  float x[FPS_P], y[FPS_P], z[FPS_P], d2m[FPS_P];
#pragma unroll
  for (int j = 0; j < FPS_P; ++j) {
    const int p = t + j * FPS_T;
    x[j] = cb[p * 3 + 0];
    y[j] = cb[p * 3 + 1];
    z[j] = cb[p * 3 + 2];
    d2m[j] = 1e20f;  // sqrt-space 1e10 == d2-space 1e20 (replaced at it=1)
    s_x[p] = x[j]; s_y[p] = y[j]; s_z[p] = z[j];
  }
  // staging writes are barrier-protected before first s_x[widx] read (iter 1
  // reads only after barriers A and B below).

  if (t == 0) {
    out_coords[(size_t)(b * MM) * 3 + 0] = cb[0];
    out_coords[(size_t)(b * MM) * 3 + 1] = cb[1];
    out_coords[(size_t)(b * MM) * 3 + 2] = cb[2];
  }
  float cx = cb[0], cy = cb[1], cz = cb[2];

  for (int it = 1; it < MM; ++it) {
    // --- update squared dists; thread-local max (verbatim round-4 math) ---
    float bestv = -1.0f;
#pragma unroll
    for (int j = 0; j < FPS_P; ++j) {
      const float dx = __fsub_rn(x[j], cx);
      const float dy = __fsub_rn(y[j], cy);
      const float dz = __fsub_rn(z[j], cz);
      const float d2 = __fadd_rn(__fadd_rn(__fmul_rn(dx, dx), __fmul_rn(dy, dy)),
                                 __fmul_rn(dz, dz));
      const float nd = fminf(d2m[j], d2);
      d2m[j] = nd;
      bestv = fmaxf(bestv, nd);
    }

    // --- phase 1: global max via DPP + one LDS/barrier hop ---
    const float wv = wave_max63(bestv);
    if ((t & 63) == 63) s_gpart[t >> 6] = wv;
    __syncthreads();  // A
    float gmax = s_gpart[0];
#pragma unroll
    for (int w = 1; w < FPS_T / 64; ++w) gmax = fmaxf(gmax, s_gpart[w]);

    // --- exact sqrt-space tie threshold (uniform; verbatim round-4) ---
    float lo_f;
    if (!(gmax > 0.0f)) {
      lo_f = 0.0f;
    } else {
      const float s = __fsqrt_rn(gmax);                        // == ref max dist
      const float sp = __int_as_float(__float_as_int(s) - 1);  // nextafter down
      const double mid = 0.5 * ((double)s + (double)sp);       // exact
      const double lod = mid * mid;                            // exact
      float c = (float)lod;
      if ((double)c < lod) c = __int_as_float(__float_as_int(c) + 1);  // ceil
      lo_f = c;  // d2 >= lo_f  <=>  sqrt_rn(d2) == s   (for d2 <= gmax)
    }

    // --- phase 2: min index among d2m >= lo_f (skip-guarded scan) ---
    unsigned int mi = 0xFFFFFFFFu;
    if (bestv >= lo_f) {  // most waves skip via execz
#pragma unroll
      for (int j = 0; j < FPS_P; ++j) {
        const unsigned int pi = (unsigned int)(t + j * FPS_T);
        if (d2m[j] >= lo_f && pi < mi) mi = pi;
      }
    }
    const unsigned int wi = wave_minu63(mi);
    if ((t & 63) == 63) s_ipart[t >> 6] = wi;
    __syncthreads();  // B
    unsigned int widx = s_ipart[0];
#pragma unroll
    for (int w = 1; w < FPS_T / 64; ++w) widx = s_ipart[w] < widx ? s_ipart[w] : widx;

    // --- centroid broadcast: uniform-address LDS read (no barrier C) ---
    cx = s_x[widx]; cy = s_y[widx]; cz = s_z[widx];
    if (t == (it & (FPS_T - 1))) {  // off-critical-path global store
      float* oc = out_coords + ((size_t)b * MM + it) * 3;
      oc[0] = cx; oc[1] = cy; oc[2] = cz;
    }
  }
}

// ---------------------------------------------------------------------------
// KNN top-32 + feature mean. Packed u64 key (flipped-d2-bits<<32 | idx) gives
// exact (d2, idx) lexicographic min == lax.top_k stable order. Per round:
// DPP u64 wave-min -> 1 partial/wave -> ONE barrier (double-buffered
// partials) -> winner; owner invalidates via STATIC-index select (rule #20:
// no runtime-indexed register arrays -> no scratch).
// ---------------------------------------------------------------------------
__global__ __launch_bounds__(256, 4)
void knn_mean_kernel(const float* __restrict__ coords,
                     const float* __restrict__ feats,
                     const float* __restrict__ out_coords,
                     float* __restrict__ out_feats) {
  const int q = blockIdx.x;   // b*MM + m
  const int b = q >> 11;
  const int t = threadIdx.x;
  const float* cb = coords + (size_t)b * NN * 3;

  const float cx = out_coords[(size_t)q * 3 + 0];
  const float cy = out_coords[(size_t)q * 3 + 1];
  const float cz = out_coords[(size_t)q * 3 + 2];
  const float c2 = __fadd_rn(__fadd_rn(__fmul_rn(cx, cx), __fmul_rn(cy, cy)),
                             __fmul_rn(cz, cz));

  unsigned long long key[32];
  unsigned long long lmin = ~0ULL;
#pragma unroll
  for (int j = 0; j < 32; ++j) {
    const int p = t + j * 256;
    const float px = cb[p * 3 + 0], py = cb[p * 3 + 1], pz = cb[p * 3 + 2];
    const float p2 = __fadd_rn(__fadd_rn(__fmul_rn(px, px), __fmul_rn(py, py)),
                               __fmul_rn(pz, pz));
    const float dot = __fmaf_rn(cz, pz, __fmaf_rn(cy, py, __fmul_rn(cx, px)));
    const float d2 = __fsub_rn(__fadd_rn(c2, p2), __fadd_rn(dot, dot));
    unsigned int ub = __float_as_uint(d2);                // order-preserving flip
    ub ^= (((unsigned int)((int)ub >> 31)) | 0x80000000u);
    key[j] = ((unsigned long long)ub << 32) | (unsigned int)p;
    lmin = key[j] < lmin ? key[j] : lmin;
  }

  __shared__ unsigned long long s_pmin[2][4];  // double-buffered wave partials
  __shared__ int s_nbr[KK];

  for (int r = 0; r < KK; ++r) {
    const unsigned long long wv = wave_minu64_63(lmin);
    if ((t & 63) == 63) s_pmin[r & 1][t >> 6] = wv;
    __syncthreads();  // one barrier per round; buffer reused every 2 rounds

    const unsigned long long* pm = s_pmin[r & 1];
    unsigned long long g = pm[0];
    g = pm[1] < g ? pm[1] : g;
    g = pm[2] < g ? pm[2] : g;
    g = pm[3] < g ? pm[3] : g;
    const int widx = (int)(unsigned int)(g & 0xFFFFFFFFull);

    if (t == (widx & 255)) {  // owner: static-index invalidate + repair lmin
      unsigned long long nm = ~0ULL;
#pragma unroll
      for (int j = 0; j < 32; ++j) {
        key[j] = (key[j] == g) ? ~0ULL : key[j];
        nm = key[j] < nm ? key[j] : nm;
      }
      lmin = nm;
    }
    if (t == 0) s_nbr[r] = widx;
  }
  __syncthreads();  // s_nbr complete

  // --- feature mean: thread t -> channel t&127, half t>>7 sums 16 rows ---
  const int c = t & (CC - 1);
  const int half = t >> 7;
  const float* fb = feats + (size_t)b * NN * CC;
  float s = 0.0f;
#pragma unroll
  for (int k = 0; k < 16; ++k) {
    const int p = s_nbr[half * 16 + k];
    s = __fadd_rn(s, fb[(size_t)p * CC + c]);
  }
  __shared__ float s_sum[CC];
  if (half == 1) s_sum[c] = s;
  __syncthreads();
  if (half == 0) {
    const float tot = __fadd_rn(s, s_sum[c]);        // (k0..15)+(k16..31)
    out_feats[(size_t)q * CC + c] = tot * 0.03125f;  // exact /32
  }
}

// ---------------------------------------------------------------------------
extern "C" void kernel_launch(void* const* d_in, const int* in_sizes, int n_in,
                              void* d_out, int out_size, void* d_ws, size_t ws_size,
                              hipStream_t stream) {
  const float* coords = (const float*)d_in[0];
  const float* feats  = (const float*)d_in[1];
  float* out_coords = (float*)d_out;                        // B*M*3
  float* out_feats  = (float*)d_out + (size_t)BB * MM * 3;  // B*M*C

  fps_kernel<<<BB, FPS_T, 0, stream>>>(coords, out_coords);
  knn_mean_kernel<<<BB * MM, 256, 0, stream>>>(coords, feats, out_coords,
                                               out_feats);
}